// Round 1
// baseline (211.813 us; speedup 1.0000x reference)
//
#include <hip/hip_runtime.h>
#include <hip/hip_bf16.h>
#include <cstdint>
#include <cmath>

#define DEVINL __device__ __forceinline__

typedef __attribute__((ext_vector_type(8))) __bf16 b8;   // MFMA A/B operand (4 VGPRs)
typedef __attribute__((ext_vector_type(8))) short  s8;   // raw 16B loads of bf16 data
typedef __attribute__((ext_vector_type(4))) float  f4;   // MFMA C/D

// f32 -> bf16 round-to-nearest-even (finite inputs only)
DEVINL unsigned short f2bf(float f){
  unsigned int u = __float_as_uint(f);
  u += 0x7FFFu + ((u >> 16) & 1u);
  return (unsigned short)(u >> 16);
}

// async global->LDS, 16B per lane; LDS dest must be wave-uniform (HW adds lane*16)
DEVINL void gl_lds16(const void* g, void* l){
  __builtin_amdgcn_global_load_lds(
      (const __attribute__((address_space(1))) void*)g,
      (__attribute__((address_space(3))) void*)l, 16, 0, 0);
}

DEVINL f4 mfma_bf16(b8 a, b8 b, f4 c){
  return __builtin_amdgcn_mfma_f32_16x16x32_bf16(a, b, c, 0, 0, 0);
}

// ---------------- prep kernels ----------------

__global__ __launch_bounds__(256) void cast_bf16_k(const float* __restrict__ in,
                                                   unsigned short* __restrict__ out, int n4){
  int stride = gridDim.x * blockDim.x;
  for (int i = blockIdx.x * blockDim.x + threadIdx.x; i < n4; i += stride){
    float4 v = ((const float4*)in)[i];
    ushort4 o; o.x = f2bf(v.x); o.y = f2bf(v.y); o.z = f2bf(v.z); o.w = f2bf(v.w);
    ((ushort4*)out)[i] = o;
  }
}

// in [K][N] f32 -> out [N][K] bf16
__global__ __launch_bounds__(256) void transpose_cast_k(const float* __restrict__ in,
                                                        unsigned short* __restrict__ out,
                                                        int K, int N){
  __shared__ float t[32][33];
  int nx = blockIdx.x * 32, kx = blockIdx.y * 32;
  int tx = threadIdx.x & 31, ty = threadIdx.x >> 5;  // ty 0..7
  #pragma unroll
  for (int i = 0; i < 4; i++)
    t[ty + 8*i][tx] = in[(size_t)(kx + ty + 8*i) * N + nx + tx];
  __syncthreads();
  #pragma unroll
  for (int i = 0; i < 4; i++)
    out[(size_t)(nx + ty + 8*i) * K + kx + tx] = f2bf(t[tx][ty + 8*i]);
}

// rtab[n][i] = (cos(n*invf_i), sin(n*invf_i)), i = d/2, 0..31
__global__ __launch_bounds__(256) void rope_tab_k(float2* __restrict__ rt){
  int t = blockIdx.x * 256 + threadIdx.x;      // 65536 total
  int n = t >> 5, i = t & 31;
  float invf = expf(-(float)i * (9.210340371976184f / 32.0f)); // 10000^(-i/32)
  float ph = (float)n * invf;
  float s, c;
  sincosf(ph, &s, &c);
  rt[t] = make_float2(c, s);
}

// ---------------- 128x128 GEMM (m97 structure), K=1024 fixed ----------------
// A [M][1024] bf16 row-major, Bt [N][1024] bf16 (i.e. B^T).
// EPI=0: qkv epilogue (RoPE on q,k; scatter to Qg/Kg/Vg [32][2048][64] bf16)
// EPI=1: plain f32 store to Of [M][N]

template<int EPI>
__global__ __launch_bounds__(256) void gemm128_k(const unsigned short* __restrict__ A,
                                                 const unsigned short* __restrict__ Bt, int N,
                                                 float* __restrict__ Of,
                                                 unsigned short* __restrict__ Qg,
                                                 unsigned short* __restrict__ Kg,
                                                 unsigned short* __restrict__ Vg,
                                                 const float2* __restrict__ rtab){
  constexpr int K = 1024;
  __shared__ unsigned short As[128 * 32];
  __shared__ unsigned short Bs[128 * 32];
  const int tid = threadIdx.x, w = tid >> 6, l = tid & 63;
  const int wr = w >> 1, wc = w & 1;
  const int m0 = blockIdx.y * 128, n0 = blockIdx.x * 128;

  f4 acc[4][4];
  const f4 fz = {0.f, 0.f, 0.f, 0.f};
  #pragma unroll
  for (int i = 0; i < 4; i++)
    #pragma unroll
    for (int j = 0; j < 4; j++) acc[i][j] = fz;

  for (int kt = 0; kt < K / 32; ++kt){
    __syncthreads();
    #pragma unroll
    for (int c = 0; c < 2; c++){
      int row = w * 32 + c * 16 + (l >> 2);           // 16 rows per call, 4 lanes/row
      gl_lds16(A + (size_t)(m0 + row) * K + kt * 32 + (l & 3) * 8,
               (char*)As + (w * 32 + c * 16) * 64);
      gl_lds16(Bt + (size_t)(n0 + row) * K + kt * 32 + (l & 3) * 8,
               (char*)Bs + (w * 32 + c * 16) * 64);
    }
    __syncthreads();
    b8 af[4], bfr[4];
    #pragma unroll
    for (int mi = 0; mi < 4; mi++)
      af[mi] = *(const b8*)&As[(wr * 64 + mi * 16 + (l & 15)) * 32 + (l >> 4) * 8];
    #pragma unroll
    for (int ni = 0; ni < 4; ni++)
      bfr[ni] = *(const b8*)&Bs[(wc * 64 + ni * 16 + (l & 15)) * 32 + (l >> 4) * 8];
    #pragma unroll
    for (int mi = 0; mi < 4; mi++)
      #pragma unroll
      for (int ni = 0; ni < 4; ni++)
        acc[mi][ni] = mfma_bf16(af[mi], bfr[ni], acc[mi][ni]);
  }

  if constexpr (EPI == 0){
    const int s = n0 >> 10;                     // 0=q 1=k 2=v (uniform per block)
    #pragma unroll
    for (int mi = 0; mi < 4; mi++){
      #pragma unroll
      for (int ni = 0; ni < 4; ni++){
        f4 a = acc[mi][ni];
        int c = n0 + wc * 64 + ni * 16 + (l & 15);
        int d = c & 63;
        int h = (c >> 6) & 15;
        #pragma unroll
        for (int jj = 0; jj < 4; jj++){
          int m = m0 + wr * 64 + mi * 16 + (l >> 4) * 4 + jj;
          int bb = m >> 11, ns = m & 2047;
          size_t didx = ((size_t)(bb * 16 + h) * 2048 + ns) * 64 + d;
          if (s == 2){
            Vg[didx] = f2bf(a[jj]);
          } else {
            float part = __shfl_xor(a[jj], 1);       // pair partner (d^1)
            float2 cs = rtab[ns * 32 + (d >> 1)];
            float val = (d & 1) ? (a[jj] * cs.x + part * cs.y)
                                : (a[jj] * cs.x - part * cs.y);
            (s == 0 ? Qg : Kg)[didx] = f2bf(val);
          }
        }
      }
    }
  } else {
    #pragma unroll
    for (int mi = 0; mi < 4; mi++)
      #pragma unroll
      for (int ni = 0; ni < 4; ni++){
        int c = n0 + wc * 64 + ni * 16 + (l & 15);
        #pragma unroll
        for (int jj = 0; jj < 4; jj++){
          int m = m0 + wr * 64 + mi * 16 + (l >> 4) * 4 + jj;
          Of[(size_t)m * N + c] = acc[mi][ni][jj];
        }
      }
  }
}

// ---------------- flash attention (swapped QK^T), head-parallel ----------------
// Qg/Kg/Vg: [32][2048][64] bf16. Ao: [4096][1024] bf16 ([b*2048+n][h*64+d]).
// Block: 256 thr (4 waves), 128 q-rows/block (32/wave), KV tiles of 64.

__global__ __launch_bounds__(256) void attn_k(const unsigned short* __restrict__ Qg,
                                              const unsigned short* __restrict__ Kg,
                                              const unsigned short* __restrict__ Vg,
                                              unsigned short* __restrict__ Ao){
  __shared__ unsigned short Ks[64 * 64];        // [kv][d], XOR-swizzled chunks
  __shared__ unsigned short Vt[64 * 64];        // [d][kv], transposed + swizzled
  __shared__ unsigned short Ps[4][32 * 64];     // per-wave P [q][kv], swizzled
  const int tid = threadIdx.x, w = tid >> 6, l = tid & 63;
  const int g = blockIdx.y;
  const size_t hb = (size_t)g * 2048 * 64;
  const int q0 = blockIdx.x * 128 + w * 32;
  unsigned short* PsW = Ps[w];

  // hoist Q fragments: qf[cb][kd] -> Q[q0+16cb+(l&15)][32kd + 8*(l>>4) .. +7]
  b8 qf[2][2];
  #pragma unroll
  for (int cb = 0; cb < 2; cb++)
    #pragma unroll
    for (int kd = 0; kd < 2; kd++)
      qf[cb][kd] = *(const b8*)(Qg + hb + (size_t)(q0 + cb * 16 + (l & 15)) * 64
                                + kd * 32 + (l >> 4) * 8);

  f4 O[2][4];
  const f4 fz = {0.f, 0.f, 0.f, 0.f};
  #pragma unroll
  for (int i = 0; i < 2; i++)
    #pragma unroll
    for (int j = 0; j < 4; j++) O[i][j] = fz;
  float mreg[2] = {-INFINITY, -INFINITY};
  float lreg[2] = {0.f, 0.f};

  for (int kv0 = 0; kv0 < 2048; kv0 += 64){
    __syncthreads();
    // K tile: global_load_lds with pre-swizzled SOURCE chunk (rule 21)
    #pragma unroll
    for (int c = 0; c < 2; c++){
      int r = w * 16 + c * 8 + (l >> 3);
      int sc = (l & 7) ^ ((l >> 3) & 7);        // src chunk = dest chunk ^ (row&7)
      gl_lds16((const char*)(Kg + hb + (size_t)(kv0 + r) * 64) + sc * 16,
               (char*)Ks + (w * 16 + c * 8) * 128);
    }
    // V tile: reg-stage transposed into Vt[d][kv], swizzled
    {
      const unsigned short* vs = Vg + hb + (size_t)(kv0 + l) * 64 + w * 16;
      s8 v0 = *(const s8*)vs;
      s8 v1 = *(const s8*)(vs + 8);
      #pragma unroll
      for (int i = 0; i < 8; i++){
        int d = w * 16 + i;
        Vt[d * 64 + (l ^ ((d & 7) << 3))] = (unsigned short)v0[i];
      }
      #pragma unroll
      for (int i = 0; i < 8; i++){
        int d = w * 16 + 8 + i;
        Vt[d * 64 + (l ^ ((d & 7) << 3))] = (unsigned short)v1[i];
      }
    }
    __syncthreads();

    // S^T = K * Q^T : st[rb][cb], rows=kv, cols=q
    f4 st[4][2];
    #pragma unroll
    for (int i = 0; i < 4; i++){ st[i][0] = fz; st[i][1] = fz; }
    #pragma unroll
    for (int kd = 0; kd < 2; kd++){
      b8 ak[4];
      #pragma unroll
      for (int rb = 0; rb < 4; rb++){
        int r = rb * 16 + (l & 15);
        ak[rb] = *(const b8*)&Ks[r * 64 + ((kd * 32 + (l >> 4) * 8) ^ ((l & 7) << 3))];
      }
      #pragma unroll
      for (int rb = 0; rb < 4; rb++)
        #pragma unroll
        for (int cb = 0; cb < 2; cb++)
          st[rb][cb] = mfma_bf16(ak[rb], qf[cb][kd], st[rb][cb]);
    }

    // online softmax per cb (lane owns q = 16cb + (l&15); kv spread over groups)
    #pragma unroll
    for (int cb = 0; cb < 2; cb++){
      float sv[16];
      float mx = -INFINITY;
      #pragma unroll
      for (int rb = 0; rb < 4; rb++)
        #pragma unroll
        for (int jj = 0; jj < 4; jj++){
          float x = st[rb][cb][jj] * 0.125f;
          sv[rb * 4 + jj] = x;
          mx = fmaxf(mx, x);
        }
      mx = fmaxf(mx, __shfl_xor(mx, 16));
      mx = fmaxf(mx, __shfl_xor(mx, 32));
      float mnew = fmaxf(mreg[cb], mx);
      float alpha = __expf(mreg[cb] - mnew);
      mreg[cb] = mnew;
      float psum = 0.f;
      unsigned int pw[8];
      #pragma unroll
      for (int t8 = 0; t8 < 8; t8++){
        float p0 = __expf(sv[2 * t8] - mnew);
        float p1 = __expf(sv[2 * t8 + 1] - mnew);
        psum += p0 + p1;
        pw[t8] = (unsigned int)f2bf(p0) | ((unsigned int)f2bf(p1) << 16);
      }
      psum += __shfl_xor(psum, 16);
      psum += __shfl_xor(psum, 32);
      lreg[cb] = lreg[cb] * alpha + psum;
      // write P to per-wave LDS [q][kv], swizzled; DS ops are wave-ordered
      int q = cb * 16 + (l & 15);
      #pragma unroll
      for (int rb = 0; rb < 4; rb++)
        #pragma unroll
        for (int jp = 0; jp < 2; jp++){
          int off = rb * 16 + (l >> 4) * 4 + jp * 2;
          *(unsigned int*)&PsW[q * 64 + (off ^ ((l & 7) << 3))] = pw[rb * 2 + jp];
        }
      // broadcast alpha to O-layout rows and rescale
      float a_[4];
      #pragma unroll
      for (int jj = 0; jj < 4; jj++) a_[jj] = __shfl(alpha, (l >> 4) * 4 + jj);
      #pragma unroll
      for (int nb = 0; nb < 4; nb++){
        f4 o = O[cb][nb];
        o[0] *= a_[0]; o[1] *= a_[1]; o[2] *= a_[2]; o[3] *= a_[3];
        O[cb][nb] = o;
      }
    }

    // PV: O[qb][nb] += P[q][kv] * V[kv][d]
    #pragma unroll
    for (int kb = 0; kb < 2; kb++){
      b8 pa[2], bv[4];
      #pragma unroll
      for (int qb = 0; qb < 2; qb++){
        int q = qb * 16 + (l & 15);
        pa[qb] = *(const b8*)&PsW[q * 64 + ((kb * 32 + (l >> 4) * 8) ^ ((l & 7) << 3))];
      }
      #pragma unroll
      for (int nb = 0; nb < 4; nb++){
        int d = nb * 16 + (l & 15);
        bv[nb] = *(const b8*)&Vt[d * 64 + ((kb * 32 + (l >> 4) * 8) ^ ((d & 7) << 3))];
      }
      #pragma unroll
      for (int qb = 0; qb < 2; qb++)
        #pragma unroll
        for (int nb = 0; nb < 4; nb++)
          O[qb][nb] = mfma_bf16(pa[qb], bv[nb], O[qb][nb]);
    }
  }

  // finalize: O /= l, store bf16 to Ao[b*2048+n][h*64+d]
  const int bb = g >> 4, h = g & 15;
  #pragma unroll
  for (int qb = 0; qb < 2; qb++){
    float li[4];
    #pragma unroll
    for (int jj = 0; jj < 4; jj++)
      li[jj] = 1.0f / __shfl(lreg[qb], (l >> 4) * 4 + jj);
    #pragma unroll
    for (int nb = 0; nb < 4; nb++){
      int d = nb * 16 + (l & 15);
      #pragma unroll
      for (int jj = 0; jj < 4; jj++){
        int qrow = q0 + qb * 16 + (l >> 4) * 4 + jj;
        Ao[(size_t)(bb * 2048 + qrow) * 1024 + h * 64 + d] = f2bf(O[qb][nb][jj] * li[jj]);
      }
    }
  }
}

// ---------------- launch ----------------

extern "C" void kernel_launch(void* const* d_in, const int* in_sizes, int n_in,
                              void* d_out, int out_size, void* d_ws, size_t ws_size,
                              hipStream_t stream){
  const float* x     = (const float*)d_in[0];   // [2,2048,1024]
  const float* wqkv  = (const float*)d_in[1];   // [1024,3072]
  const float* wproj = (const float*)d_in[2];   // [1024,1024]
  float* out = (float*)d_out;                   // [2,2048,1024] f32

  if (ws_size < 42467328u) return;              // fail loudly (poisoned output)
  char* ws = (char*)d_ws;
  unsigned short* xb     = (unsigned short*)(ws);             // 8 MB
  unsigned short* wqkvT  = (unsigned short*)(ws + 8388608);   // 6 MB  [3072][1024]
  unsigned short* wprojT = (unsigned short*)(ws + 14680064);  // 2 MB  [1024][1024]
  float2*         rtab   = (float2*)(ws + 16777216);          // 512 KB
  unsigned short* Qg     = (unsigned short*)(ws + 17301504);  // 8 MB  [32][2048][64]
  unsigned short* Kg     = (unsigned short*)(ws + 25690112);  // 8 MB
  unsigned short* Vg     = (unsigned short*)(ws + 34078720);  // 8 MB
  unsigned short* Ao     = xb;                                // reuse (xb dead after QKV gemm)

  cast_bf16_k<<<2048, 256, 0, stream>>>(x, xb, 4096 * 1024 / 4);
  transpose_cast_k<<<dim3(96, 32), 256, 0, stream>>>(wqkv, wqkvT, 1024, 3072);
  transpose_cast_k<<<dim3(32, 32), 256, 0, stream>>>(wproj, wprojT, 1024, 1024);
  rope_tab_k<<<256, 256, 0, stream>>>(rtab);
  gemm128_k<0><<<dim3(24, 32), 256, 0, stream>>>(xb, wqkvT, 3072, nullptr, Qg, Kg, Vg, rtab);
  attn_k<<<dim3(16, 32), 256, 0, stream>>>(Qg, Kg, Vg, Ao);
  gemm128_k<1><<<dim3(8, 32), 256, 0, stream>>>(Ao, wprojT, 1024, out, nullptr, nullptr, nullptr, nullptr);
}